// Round 5
// baseline (223.799 us; speedup 1.0000x reference)
//
#include <hip/hip_runtime.h>
#include <hip/hip_bf16.h>
#include <stdint.h>

#define LAG 5
#define NROW 4096
#define NREG 500
#define NTGT 500
#define O_REAL 8000     /* HH*NTGT */
#define KP 2560         /* padded K = 40*64  (real K = 2500) */
#define NPAD 8192       /* GEMM N extent = 32*256 (cols >= 8000 masked) */
#define BK 64
#define NT 40           /* K-tiles */

typedef __bf16 bf16x8 __attribute__((ext_vector_type(8)));
typedef float f32x4 __attribute__((ext_vector_type(4)));
typedef float f32x16 __attribute__((ext_vector_type(16)));

__device__ __forceinline__ unsigned short f2bf(float f) {
  unsigned u = __float_as_uint(f);
  return (unsigned short)((u + 0x7fffu + ((u >> 16) & 1u)) >> 16);
}

__device__ __forceinline__ void async16(void* lds_base, const void* g) {
  __builtin_amdgcn_global_load_lds(
      (const __attribute__((address_space(1))) unsigned int*)g,
      (__attribute__((address_space(3))) unsigned int*)lds_base,
      16, 0, 0);
}

// ---------------- convert AX [5][4096][500] f32 -> A' [4096][2560] bf16 (k = l*500+r, zero pad) ----
__global__ __launch_bounds__(256) void convA(const float* __restrict__ AX,
                                             unsigned short* __restrict__ Ab) {
  int idx = blockIdx.x * 256 + threadIdx.x;
  if (idx >= NROW * (KP / 4)) return;
  int n = idx / (KP / 4);
  int c4 = idx - n * (KP / 4);
  int k = c4 * 4;
  ushort4 o;
  if (k < LAG * NREG) {
    int l = k / NREG, r = k - l * NREG;
    float4 v = *(const float4*)(AX + ((size_t)l * NROW + n) * NREG + r);
    o.x = f2bf(v.x); o.y = f2bf(v.y); o.z = f2bf(v.z); o.w = f2bf(v.w);
  } else {
    o.x = 0; o.y = 0; o.z = 0; o.w = 0;
  }
  *(ushort4*)(Ab + (size_t)idx * 4) = o;
}

// ---------------- convert W0 [8000][500][5] f32 -> B' [8192][2560] bf16 (lag-reversed) ------------
__global__ __launch_bounds__(256) void convB(const float* __restrict__ W0,
                                             unsigned short* __restrict__ Bb) {
  int idx = blockIdx.x * 256 + threadIdx.x;
  if (idx >= O_REAL * NREG) return;
  int o = idx / NREG, r = idx - o * NREG;
  const float* s = W0 + (size_t)idx * LAG;
  #pragma unroll
  for (int j = 0; j < LAG; ++j)
    Bb[(size_t)o * KP + (size_t)(LAG - 1 - j) * NREG + r] = f2bf(s[j]);
}

// ---------------- zero B' pad: k in [2500,2560) for rows < 8000; rows [8000,8192) fully ----------
__global__ __launch_bounds__(256) void padB(unsigned short* __restrict__ Bb) {
  int idx = blockIdx.x * 256 + threadIdx.x;         // ushort4 units
  const int A4 = O_REAL * 15;                       // 60 pad elems/row = 15 x ushort4
  ushort4 z; z.x = 0; z.y = 0; z.z = 0; z.w = 0;
  if (idx < A4) {
    int row = idx / 15, c4 = idx - row * 15;
    *(ushort4*)(Bb + (size_t)row * KP + 2500 + c4 * 4) = z;
  } else {
    int j = idx - A4;
    if (j < 192 * (KP / 4))
      *(ushort4*)(Bb + (size_t)O_REAL * KP + (size_t)j * 4) = z;
  }
}

// ---------------- 256x256 8-phase bf16 GEMM (32x32x16 MFMA) + fused MLP tail --------------------
// K-loop v5: v4's verified schedule (12/4/8/0 reads, 1 stage/phase, vmcnt(4) gates) with the MFMA
// shape switched 16x16x32 -> 32x32x16 (2382 vs 2075 TF ubench; half the MFMA instructions).
// Per-wave output 128x64 = 4M x 2N frags of 32x32. Per phase: 8 MFMA (2 mi-chains x 4 ksteps).
//   ph1: read A01(8R)+Bn0(4R); stage A(t+1)h0   | mi01 x ni0
//   ph2: read Bn1(4R);         stage A(t+1)h1   | mi01 x ni1
//   ph3: read A23(8R);         stage B(t+2)h0   | mi23 x ni0
//   ph4:                       stage B(t+2)h1; GATE vmcnt(4) | mi23 x ni1
// Hazards identical to v4 (B reads retire ph2-END, A reads ph3-END).
__global__ __launch_bounds__(512, 2) void gemm8(const unsigned short* __restrict__ A,
                                                const unsigned short* __restrict__ B,
                                                const float* __restrict__ b0,
                                                const float* __restrict__ W1g,
                                                const float* __restrict__ b1g,
                                                const float* __restrict__ W2g,
                                                const float* __restrict__ b2g,
                                                float* __restrict__ out) {
  extern __shared__ char smem[];
  char* sAc = smem;            // [2][32768]
  char* sBc = smem + 65536;    // [2][32768]

  int bid = blockIdx.x;
  int swz = (bid & 7) * 64 + (bid >> 3);       // XCD-aware, bijective (512 % 8 == 0)
  int mt = swz & 15, ntile = swz >> 4;         // 16 M-tiles x 32 N-tiles
  int row0 = mt * 256, col0 = ntile * 256;

  int tid = threadIdx.x, l = tid & 63, w = tid >> 6;
  int wr = w >> 2, wc = w & 3;

  // staging source pointers (pre-swizzled global source, linear LDS dest)
  int sr = l >> 3;                 // row within 8-row chunk
  int ss = (l & 7) ^ sr;           // swizzled 16B slot
  const unsigned short* gApre0 = A + (size_t)(row0 + (w * 2 + 0) * 8 + sr) * KP + ss * 8;
  const unsigned short* gApre1 = A + (size_t)(row0 + (w * 2 + 1) * 8 + sr) * KP + ss * 8;
  const unsigned short* gBpre0 = B + (size_t)(col0 + (w * 2 + 0) * 8 + sr) * KP + ss * 8;
  const unsigned short* gBpre1 = B + (size_t)(col0 + (w * 2 + 1) * 8 + sr) * KP + ss * 8;

#define STG_A(buf, half, t) do { \
    async16(sAc + (buf) * 32768 + (half) * 16384 + (w * 2 + 0) * 1024, gApre0 + (size_t)(half) * 128 * KP + (size_t)(t) * BK); \
    async16(sAc + (buf) * 32768 + (half) * 16384 + (w * 2 + 1) * 1024, gApre1 + (size_t)(half) * 128 * KP + (size_t)(t) * BK); \
  } while (0)
#define STG_B(buf, half, t) do { \
    async16(sBc + (buf) * 32768 + (half) * 16384 + (w * 2 + 0) * 1024, gBpre0 + (size_t)(half) * 128 * KP + (size_t)(t) * BK); \
    async16(sBc + (buf) * 32768 + (half) * 16384 + (w * 2 + 1) * 1024, gBpre1 + (size_t)(half) * 128 * KP + (size_t)(t) * BK); \
  } while (0)

  // 32x32 fragment addressing: lane l holds row (l&31), k-elems (l>>5)*8 .. +7 of each 32x16 step.
  // row&7 == l&7 for all fragment rows -> same XOR swizzle as staging.
  int hi = l >> 5;
  int sw8 = (l & 7) << 4;
  int arowb = (wr * 128 + (l & 31)) * 128;     // byte offset of A row
  int browb = (wc * 64 + (l & 31)) * 128;      // byte offset of B row

  auto lda32 = [&](int buf, int mi, int ks) -> bf16x8 {
    return *(const bf16x8*)(sAc + buf * 32768 + arowb + mi * 4096 + ((((ks * 2 + hi) << 4)) ^ sw8));
  };
  auto ldb32 = [&](int buf, int ni, int ks) -> bf16x8 {
    return *(const bf16x8*)(sBc + buf * 32768 + browb + ni * 4096 + ((((ks * 2 + hi) << 4)) ^ sw8));
  };

  f32x16 acc[4][2];
  #pragma unroll
  for (int i = 0; i < 4; ++i)
    #pragma unroll
    for (int j = 0; j < 2; ++j)
      #pragma unroll
      for (int r = 0; r < 16; ++r) acc[i][j][r] = 0.f;

#define PH_SYNC() do { __builtin_amdgcn_s_barrier(); \
    asm volatile("s_waitcnt lgkmcnt(0)" ::: "memory"); \
    __builtin_amdgcn_s_setprio(1); } while (0)
#define PH_END() do { __builtin_amdgcn_s_setprio(0); __builtin_amdgcn_s_barrier(); } while (0)

// 8 MFMA: 2 independent mi chains x 4 dependent ksteps, into acc[M0..M0+1][NI]
#define MFMA_P(M0, AF, BV, NI) do { \
    _Pragma("unroll") \
    for (int ks = 0; ks < 4; ++ks) { \
      acc[(M0) + 0][NI] = __builtin_amdgcn_mfma_f32_32x32x16_bf16(AF[0][ks], BV[ks], acc[(M0) + 0][NI], 0, 0, 0); \
      acc[(M0) + 1][NI] = __builtin_amdgcn_mfma_f32_32x32x16_bf16(AF[1][ks], BV[ks], acc[(M0) + 1][NI], 0, 0, 0); \
    } \
  } while (0)

  // prologue: T0 full {B,A} + T1.B -> 12 loads/thread; gate T0 (T1.B's 4 in flight)
  STG_B(0, 0, 0); STG_B(0, 1, 0); STG_A(0, 0, 0); STG_A(0, 1, 0);
  STG_B(1, 0, 1); STG_B(1, 1, 1);
  asm volatile("s_waitcnt vmcnt(4)" ::: "memory");
  __builtin_amdgcn_s_barrier();

  for (int t = 0; t < NT; t += 2) {
    const bool last = (t == NT - 2);
    bf16x8 a01[2][4], a23[2][4], b0v[4], b1v[4];

    // ---- ph1: read A01 (8R) + Bn0 (4R) (buf0); stage A(t+1)->buf1.h0
    #pragma unroll
    for (int ks = 0; ks < 4; ++ks) b0v[ks] = ldb32(0, 0, ks);
    #pragma unroll
    for (int mi = 0; mi < 2; ++mi)
      #pragma unroll
      for (int ks = 0; ks < 4; ++ks) a01[mi][ks] = lda32(0, mi, ks);
    STG_A(1, 0, t + 1);
    asm volatile("s_waitcnt lgkmcnt(8)" ::: "memory");
    PH_SYNC(); MFMA_P(0, a01, b0v, 0); PH_END();

    // ---- ph2: read Bn1 (4R); stage A(t+1)->buf1.h1
    #pragma unroll
    for (int ks = 0; ks < 4; ++ks) b1v[ks] = ldb32(0, 1, ks);
    STG_A(1, 1, t + 1);
    PH_SYNC(); MFMA_P(0, a01, b1v, 1); PH_END();

    // ---- ph3: read A23 (8R); stage B(t+2)->buf0.h0 (buf0.B reads retired ph2-END)
    #pragma unroll
    for (int mi = 0; mi < 2; ++mi)
      #pragma unroll
      for (int ks = 0; ks < 4; ++ks) a23[mi][ks] = lda32(0, 2 + mi, ks);
    if (!last) STG_B(0, 0, t + 2);
    PH_SYNC(); MFMA_P(2, a23, b0v, 0); PH_END();

    // ---- ph4: stage B(t+2)->buf0.h1; GATE tile t+1 (vmcnt(4))
    if (!last) STG_B(0, 1, t + 2);
    if (last) asm volatile("s_waitcnt vmcnt(0)" ::: "memory");
    else      asm volatile("s_waitcnt vmcnt(4)" ::: "memory");
    __builtin_amdgcn_s_barrier();
    asm volatile("s_waitcnt lgkmcnt(0)" ::: "memory");
    __builtin_amdgcn_s_setprio(1);
    MFMA_P(2, a23, b1v, 1);
    PH_END();

    // ---- ph5: read A01 + Bn0 (buf1, 12R); stage A(t+2)->buf0.h0 (buf0.A reads retired ph3-END)
    #pragma unroll
    for (int ks = 0; ks < 4; ++ks) b0v[ks] = ldb32(1, 0, ks);
    #pragma unroll
    for (int mi = 0; mi < 2; ++mi)
      #pragma unroll
      for (int ks = 0; ks < 4; ++ks) a01[mi][ks] = lda32(1, mi, ks);
    if (!last) STG_A(0, 0, t + 2);
    asm volatile("s_waitcnt lgkmcnt(8)" ::: "memory");
    PH_SYNC(); MFMA_P(0, a01, b0v, 0); PH_END();

    // ---- ph6: read Bn1 (buf1, 4R); stage A(t+2)->buf0.h1
    #pragma unroll
    for (int ks = 0; ks < 4; ++ks) b1v[ks] = ldb32(1, 1, ks);
    if (!last) STG_A(0, 1, t + 2);
    PH_SYNC(); MFMA_P(0, a01, b1v, 1); PH_END();

    // ---- ph7: read A23 (buf1, 8R); stage B(t+3)->buf1.h0 (buf1.B reads retired ph6-END)
    #pragma unroll
    for (int mi = 0; mi < 2; ++mi)
      #pragma unroll
      for (int ks = 0; ks < 4; ++ks) a23[mi][ks] = lda32(1, 2 + mi, ks);
    if (!last) STG_B(1, 0, t + 3);
    PH_SYNC(); MFMA_P(2, a23, b0v, 0); PH_END();

    // ---- ph8: stage B(t+3)->buf1.h1; GATE tile t+2 (vmcnt(4))
    if (!last) STG_B(1, 1, t + 3);
    if (last) asm volatile("s_waitcnt vmcnt(0)" ::: "memory");
    else      asm volatile("s_waitcnt vmcnt(4)" ::: "memory");
    __builtin_amdgcn_s_barrier();
    asm volatile("s_waitcnt lgkmcnt(0)" ::: "memory");
    __builtin_amdgcn_s_setprio(1);
    MFMA_P(2, a23, b1v, 1);
    __builtin_amdgcn_s_setprio(0);
    __builtin_amdgcn_s_barrier();
  }

  // ================= epilogue (v2 structure; step1 remapped for 32x32 C/D layout) =================
  // 32x32 C/D: col = lane&31, row = (reg&3) + 8*(reg>>2) + 4*(lane>>5)   [m74/m101 verified]
  int t0 = col0 >> 4;                      // first of this block's 16 targets

  float bias2[2];
  #pragma unroll
  for (int ni = 0; ni < 2; ++ni) {
    int gcol = col0 + wc * 64 + ni * 32 + (l & 31);
    bias2[ni] = (gcol < O_REAL) ? b0[gcol] : 0.f;
  }

  #pragma unroll
  for (int mi = 0; mi < 4; ++mi) {
    #pragma unroll
    for (int ni = 0; ni < 2; ++ni) {
      #pragma unroll
      for (int reg = 0; reg < 16; ++reg) {
        int rowL = wr * 128 + mi * 32 + (reg & 3) + 8 * (reg >> 2) + 4 * (l >> 5);
        int colL = wc * 64 + ni * 32 + (l & 31);
        int sw = ((rowL ^ (rowL >> 2)) & 7) << 4;
        float v = fmaxf(acc[mi][ni][reg] + bias2[ni], 0.f);
        *(unsigned short*)(smem + (size_t)rowL * 512 + ((colL * 2) ^ sw)) = f2bf(v);
      }
    }
  }
  __syncthreads();

  // Step 2: wave w owns targets 2w, 2w+1; lanes = rows. W via wave-uniform (scalar) loads.
  int uw = __builtin_amdgcn_readfirstlane(w);
  float oacc[2][4];
  #pragma unroll
  for (int g = 0; g < 2; ++g) {
    int tloc = uw * 2 + g;
    int tt = t0 + tloc;
    bool tvalid = (tt < NTGT);
    const float* w1t = W1g + (size_t)tt * 256;
    float b1v2[16], w2v[16];
    float b2v = 0.f;
    if (tvalid) {
      #pragma unroll
      for (int e4 = 0; e4 < 4; ++e4) {
        float4 ba = *(const float4*)(b1g + (size_t)tt * 16 + e4 * 4);
        float4 wa = *(const float4*)(W2g + (size_t)tt * 16 + e4 * 4);
        b1v2[e4 * 4 + 0] = ba.x; b1v2[e4 * 4 + 1] = ba.y; b1v2[e4 * 4 + 2] = ba.z; b1v2[e4 * 4 + 3] = ba.w;
        w2v[e4 * 4 + 0] = wa.x; w2v[e4 * 4 + 1] = wa.y; w2v[e4 * 4 + 2] = wa.z; w2v[e4 * 4 + 3] = wa.w;
      }
      b2v = b2g[tt];
    }
    #pragma unroll
    for (int rg = 0; rg < 4; ++rg) {
      int rowL = rg * 64 + l;
      int sw = ((rowL ^ (rowL >> 2)) & 7) << 4;
      const char* bp = smem + (size_t)rowL * 512;
      uint4 va = *(const uint4*)(bp + ((tloc * 32) ^ sw));
      uint4 vb = *(const uint4*)(bp + ((tloc * 32 + 16) ^ sw));
      unsigned q0 = va.x, q1 = va.y, q2 = va.z, q3 = va.w;
      unsigned q4 = vb.x, q5 = vb.y, q6 = vb.z, q7 = vb.w;
      float x[16];
      x[0]  = __uint_as_float(q0 << 16); x[1]  = __uint_as_float(q0 & 0xffff0000u);
      x[2]  = __uint_as_float(q1 << 16); x[3]  = __uint_as_float(q1 & 0xffff0000u);
      x[4]  = __uint_as_float(q2 << 16); x[5]  = __uint_as_float(q2 & 0xffff0000u);
      x[6]  = __uint_as_float(q3 << 16); x[7]  = __uint_as_float(q3 & 0xffff0000u);
      x[8]  = __uint_as_float(q4 << 16); x[9]  = __uint_as_float(q4 & 0xffff0000u);
      x[10] = __uint_as_float(q5 << 16); x[11] = __uint_as_float(q5 & 0xffff0000u);
      x[12] = __uint_as_float(q6 << 16); x[13] = __uint_as_float(q6 & 0xffff0000u);
      x[14] = __uint_as_float(q7 << 16); x[15] = __uint_as_float(q7 & 0xffff0000u);
      float o = 0.f;
      if (tvalid) {
        #pragma unroll
        for (int e = 0; e < 16; ++e) {
          float4 wq0 = *(const float4*)(w1t + e * 16 + 0);
          float4 wq1 = *(const float4*)(w1t + e * 16 + 4);
          float4 wq2 = *(const float4*)(w1t + e * 16 + 8);
          float4 wq3 = *(const float4*)(w1t + e * 16 + 12);
          float s = b1v2[e];
          s = fmaf(x[0],  wq0.x, s); s = fmaf(x[1],  wq0.y, s);
          s = fmaf(x[2],  wq0.z, s); s = fmaf(x[3],  wq0.w, s);
          s = fmaf(x[4],  wq1.x, s); s = fmaf(x[5],  wq1.y, s);
          s = fmaf(x[6],  wq1.z, s); s = fmaf(x[7],  wq1.w, s);
          s = fmaf(x[8],  wq2.x, s); s = fmaf(x[9],  wq2.y, s);
          s = fmaf(x[10], wq2.z, s); s = fmaf(x[11], wq2.w, s);
          s = fmaf(x[12], wq3.x, s); s = fmaf(x[13], wq3.y, s);
          s = fmaf(x[14], wq3.z, s); s = fmaf(x[15], wq3.w, s);
          s = fmaxf(s, 0.f);
          o = fmaf(s, w2v[e], o);
        }
        o += b2v;
      }
      oacc[g][rg] = o;
    }
  }
  __syncthreads();   // everyone done reading X

  // Step 3: transpose o through LDS ([256][17] f32 = 17.4 KB over dead X), coalesced out stores
  {
    float* sOut = (float*)smem;
    #pragma unroll
    for (int g = 0; g < 2; ++g) {
      int tloc = uw * 2 + g;
      #pragma unroll
      for (int rg = 0; rg < 4; ++rg)
        sOut[(rg * 64 + l) * 17 + tloc] = oacc[g][rg];
    }
    __syncthreads();
    int c = tid & 15, rr = tid >> 4;
    bool cv = (t0 + c < NTGT);
    #pragma unroll
    for (int j = 0; j < 8; ++j) {
      int row = rr + 32 * j;
      if (cv) out[(size_t)(row0 + row) * NTGT + (t0 + c)] = sOut[row * 17 + c];
    }
  }
#undef STG_A
#undef STG_B
#undef PH_SYNC
#undef PH_END
#undef MFMA_P
}

extern "C" void kernel_launch(void* const* d_in, const int* in_sizes, int n_in,
                              void* d_out, int out_size, void* d_ws, size_t ws_size,
                              hipStream_t stream) {
  const float* AX = (const float*)d_in[0];
  const float* W0 = (const float*)d_in[1];
  const float* b0 = (const float*)d_in[2];
  const float* W1 = (const float*)d_in[3];
  const float* b1 = (const float*)d_in[4];
  const float* W2 = (const float*)d_in[5];
  const float* b2 = (const float*)d_in[6];
  float* out = (float*)d_out;

  char* ws = (char*)d_ws;
  const size_t szA = (size_t)NROW * KP * 2;     // 20.97 MB
  unsigned short* Ab = (unsigned short*)ws;
  unsigned short* Bb = (unsigned short*)(ws + szA);   // [8192][2560] bf16 = 41.9 MB

  hipFuncSetAttribute((const void*)gemm8, hipFuncAttributeMaxDynamicSharedMemorySize, 131072);

  convA<<<(NROW * (KP / 4) + 255) / 256, 256, 0, stream>>>(AX, Ab);
  convB<<<(O_REAL * NREG + 255) / 256, 256, 0, stream>>>(W0, Bb);
  {
    int npad4 = O_REAL * 15 + 192 * (KP / 4);   // 242,880 ushort4 writes
    padB<<<(npad4 + 255) / 256, 256, 0, stream>>>(Bb);
  }
  gemm8<<<(NROW / 256) * (NPAD / 256), 512, 131072, stream>>>(Ab, Bb, b0, W1, b1, W2, b2, out);
}

// Round 6
// 202.185 us; speedup vs baseline: 1.1069x; 1.1069x over previous
//
#include <hip/hip_runtime.h>
#include <hip/hip_bf16.h>
#include <stdint.h>

#define LAG 5
#define NROW 4096
#define NREG 500
#define NTGT 500
#define O_REAL 8000     /* HH*NTGT */
#define KP 2560         /* padded K = 40*64  (real K = 2500) */
#define NPAD 8192       /* GEMM N extent = 32*256 (cols >= 8000 masked) */
#define BK 64
#define NT 40           /* K-tiles */

#define NBLK_A 10240    /* NROW*(KP/4)/256 */
#define NBLK_B 15625    /* O_REAL*NREG/256 */
#define NBLK_P 949      /* ceil((O_REAL*15 + 192*(KP/4))/256) */

typedef __bf16 bf16x8 __attribute__((ext_vector_type(8)));
typedef float f32x4 __attribute__((ext_vector_type(4)));

__device__ __forceinline__ unsigned short f2bf(float f) {
  unsigned u = __float_as_uint(f);
  return (unsigned short)((u + 0x7fffu + ((u >> 16) & 1u)) >> 16);
}

__device__ __forceinline__ void async16(void* lds_base, const void* g) {
  __builtin_amdgcn_global_load_lds(
      (const __attribute__((address_space(1))) unsigned int*)g,
      (__attribute__((address_space(3))) unsigned int*)lds_base,
      16, 0, 0);
}

// ---- merged prep: convA [0,NBLK_A) | convB [NBLK_A,NBLK_A+NBLK_B) | padB [rest) ----------------
// convA: AX [5][4096][500] f32 -> A' [4096][2560] bf16 (k = l*500+r, zero pad)
// convB: W0 [8000][500][5] f32 -> B' [8192][2560] bf16 (lag-reversed)
// padB : zero k in [2500,2560) rows<8000, rows [8000,8192) fully
__global__ __launch_bounds__(256) void convAll(const float* __restrict__ AX,
                                               const float* __restrict__ W0,
                                               unsigned short* __restrict__ Ab,
                                               unsigned short* __restrict__ Bb) {
  int b = blockIdx.x;
  if (b < NBLK_A) {
    int idx = b * 256 + threadIdx.x;
    int n = idx / (KP / 4);
    int c4 = idx - n * (KP / 4);
    int k = c4 * 4;
    ushort4 o;
    if (k < LAG * NREG) {
      int l = k / NREG, r = k - l * NREG;
      float4 v = *(const float4*)(AX + ((size_t)l * NROW + n) * NREG + r);
      o.x = f2bf(v.x); o.y = f2bf(v.y); o.z = f2bf(v.z); o.w = f2bf(v.w);
    } else {
      o.x = 0; o.y = 0; o.z = 0; o.w = 0;
    }
    *(ushort4*)(Ab + (size_t)idx * 4) = o;
  } else if (b < NBLK_A + NBLK_B) {
    int idx = (b - NBLK_A) * 256 + threadIdx.x;
    int o = idx / NREG, r = idx - o * NREG;
    const float* s = W0 + (size_t)idx * LAG;
    #pragma unroll
    for (int j = 0; j < LAG; ++j)
      Bb[(size_t)o * KP + (size_t)(LAG - 1 - j) * NREG + r] = f2bf(s[j]);
  } else {
    int idx = (b - NBLK_A - NBLK_B) * 256 + threadIdx.x;    // ushort4 units
    const int A4 = O_REAL * 15;                             // 60 pad elems/row
    ushort4 z; z.x = 0; z.y = 0; z.z = 0; z.w = 0;
    if (idx < A4) {
      int row = idx / 15, c4 = idx - row * 15;
      *(ushort4*)(Bb + (size_t)row * KP + 2500 + c4 * 4) = z;
    } else {
      int j = idx - A4;
      if (j < 192 * (KP / 4))
        *(ushort4*)(Bb + (size_t)O_REAL * KP + (size_t)j * 4) = z;
    }
  }
}

// ---------------- 256x256 8-phase bf16 GEMM + fused MLP tail (verified v4 K-loop) ---------------
// K-loop: 12/4/8/0 same-phase consume-reads, 1 two-load stage per phase, vmcnt(4) gates at ph4/ph8.
// Hazard map: buf0.B reads retire ph2-END -> B(t+2) staged ph3/ph4; buf0.A retire ph3-END -> A(t+2)
// ph5/ph6; buf1.B retire ph6-END -> B(t+3) ph7/ph8; buf1.A retire ph7-END -> A(t+1) ph1/ph2.
__global__ __launch_bounds__(512, 2) void gemm8(const unsigned short* __restrict__ A,
                                                const unsigned short* __restrict__ B,
                                                const float* __restrict__ b0,
                                                const float* __restrict__ W1g,
                                                const float* __restrict__ b1g,
                                                const float* __restrict__ W2g,
                                                const float* __restrict__ b2g,
                                                float* __restrict__ out) {
  extern __shared__ char smem[];
  char* sAc = smem;            // [2][32768]
  char* sBc = smem + 65536;    // [2][32768]

  int bid = blockIdx.x;
  int swz = (bid & 7) * 64 + (bid >> 3);       // XCD-aware, bijective (512 % 8 == 0)
  int mt = swz & 15, ntile = swz >> 4;         // 16 M-tiles x 32 N-tiles
  int row0 = mt * 256, col0 = ntile * 256;

  int tid = threadIdx.x, l = tid & 63, w = tid >> 6;
  int wr = w >> 2, wc = w & 3;

  // staging source pointers (pre-swizzled global source, linear LDS dest)
  int sr = l >> 3;                 // row within 8-row chunk
  int ss = (l & 7) ^ sr;           // swizzled 16B slot
  const unsigned short* gApre0 = A + (size_t)(row0 + (w * 2 + 0) * 8 + sr) * KP + ss * 8;
  const unsigned short* gApre1 = A + (size_t)(row0 + (w * 2 + 1) * 8 + sr) * KP + ss * 8;
  const unsigned short* gBpre0 = B + (size_t)(col0 + (w * 2 + 0) * 8 + sr) * KP + ss * 8;
  const unsigned short* gBpre1 = B + (size_t)(col0 + (w * 2 + 1) * 8 + sr) * KP + ss * 8;

#define STG_A(buf, half, t) do { \
    async16(sAc + (buf) * 32768 + (half) * 16384 + (w * 2 + 0) * 1024, gApre0 + (size_t)(half) * 128 * KP + (size_t)(t) * BK); \
    async16(sAc + (buf) * 32768 + (half) * 16384 + (w * 2 + 1) * 1024, gApre1 + (size_t)(half) * 128 * KP + (size_t)(t) * BK); \
  } while (0)
#define STG_B(buf, half, t) do { \
    async16(sBc + (buf) * 32768 + (half) * 16384 + (w * 2 + 0) * 1024, gBpre0 + (size_t)(half) * 128 * KP + (size_t)(t) * BK); \
    async16(sBc + (buf) * 32768 + (half) * 16384 + (w * 2 + 1) * 1024, gBpre1 + (size_t)(half) * 128 * KP + (size_t)(t) * BK); \
  } while (0)

  // fragment read offsets (row&7 == l&7 for all fragment rows)
  int arowb = (wr * 128 + (l & 15)) * 128;     // byte offset of A row
  int browb = (wc * 64 + (l & 15)) * 128;      // byte offset of B row
  int c0 = (((l >> 4) << 4)) ^ ((l & 7) << 4); // kk=0 swizzled col byte; kk=1 -> ^64

  auto lda = [&](int buf, int mi, int kk) -> bf16x8 {
    return *(const bf16x8*)(sAc + buf * 32768 + arowb + mi * 2048 + (c0 ^ (kk * 64)));
  };
  auto ldb = [&](int buf, int ni, int kk) -> bf16x8 {
    return *(const bf16x8*)(sBc + buf * 32768 + browb + ni * 2048 + (c0 ^ (kk * 64)));
  };

  f32x4 acc[8][4];
  #pragma unroll
  for (int i = 0; i < 8; ++i)
    #pragma unroll
    for (int j = 0; j < 4; ++j) acc[i][j] = (f32x4){0.f, 0.f, 0.f, 0.f};

#define PH_SYNC() do { __builtin_amdgcn_s_barrier(); \
    asm volatile("s_waitcnt lgkmcnt(0)" ::: "memory"); \
    __builtin_amdgcn_s_setprio(1); } while (0)
#define PH_END() do { __builtin_amdgcn_s_setprio(0); __builtin_amdgcn_s_barrier(); } while (0)

#define MFMA_Q(MOFF, AF, NIOFF) do { \
    _Pragma("unroll") \
    for (int mi = 0; mi < 4; ++mi) { \
      _Pragma("unroll") \
      for (int ni = 0; ni < 2; ++ni) { \
        acc[(MOFF) + mi][(NIOFF) + ni] = __builtin_amdgcn_mfma_f32_16x16x32_bf16(AF[mi][0], bb[(NIOFF) + ni][0], acc[(MOFF) + mi][(NIOFF) + ni], 0, 0, 0); \
        acc[(MOFF) + mi][(NIOFF) + ni] = __builtin_amdgcn_mfma_f32_16x16x32_bf16(AF[mi][1], bb[(NIOFF) + ni][1], acc[(MOFF) + mi][(NIOFF) + ni], 0, 0, 0); \
      } \
    } \
  } while (0)

  // prologue: T0 full {B,A} + T1.B -> 12 loads/thread; gate T0 (T1.B's 4 in flight)
  STG_B(0, 0, 0); STG_B(0, 1, 0); STG_A(0, 0, 0); STG_A(0, 1, 0);
  STG_B(1, 0, 1); STG_B(1, 1, 1);
  asm volatile("s_waitcnt vmcnt(4)" ::: "memory");
  __builtin_amdgcn_s_barrier();

  for (int t = 0; t < NT; t += 2) {
    const bool last = (t == NT - 2);
    bf16x8 a03[4][2], a47[4][2], bb[4][2];

    // ---- ph1: read bb01+a03 (buf0, 12R); stage A(t+1)->buf1.h0 (buf1.A reads retired prev ph7-END)
    #pragma unroll
    for (int ni = 0; ni < 2; ++ni) { bb[ni][0] = ldb(0, ni, 0); bb[ni][1] = ldb(0, ni, 1); }
    #pragma unroll
    for (int mi = 0; mi < 4; ++mi) { a03[mi][0] = lda(0, mi, 0); a03[mi][1] = lda(0, mi, 1); }
    STG_A(1, 0, t + 1);
    asm volatile("s_waitcnt lgkmcnt(8)" ::: "memory");
    PH_SYNC(); MFMA_Q(0, a03, 0); PH_END();

    // ---- ph2: read bb23 (4R); stage A(t+1)->buf1.h1
    #pragma unroll
    for (int ni = 2; ni < 4; ++ni) { bb[ni][0] = ldb(0, ni, 0); bb[ni][1] = ldb(0, ni, 1); }
    STG_A(1, 1, t + 1);
    PH_SYNC(); MFMA_Q(0, a03, 2); PH_END();

    // ---- ph3: read a47 (8R); stage B(t+2)->buf0.h0 (buf0.B reads retired ph2-END)
    #pragma unroll
    for (int mi = 0; mi < 4; ++mi) { a47[mi][0] = lda(0, 4 + mi, 0); a47[mi][1] = lda(0, 4 + mi, 1); }
    if (!last) STG_B(0, 0, t + 2);
    PH_SYNC(); MFMA_Q(4, a47, 0); PH_END();

    // ---- ph4: stage B(t+2)->buf0.h1; GATE tile t+1 (vmcnt(4): ph3/ph4's B(t+2) may fly)
    if (!last) STG_B(0, 1, t + 2);
    if (last) asm volatile("s_waitcnt vmcnt(0)" ::: "memory");
    else      asm volatile("s_waitcnt vmcnt(4)" ::: "memory");
    __builtin_amdgcn_s_barrier();
    asm volatile("s_waitcnt lgkmcnt(0)" ::: "memory");
    __builtin_amdgcn_s_setprio(1);
    MFMA_Q(4, a47, 2);
    PH_END();

    // ---- ph5: read bb01+a03 (buf1, 12R); stage A(t+2)->buf0.h0 (buf0.A reads retired ph3-END)
    #pragma unroll
    for (int ni = 0; ni < 2; ++ni) { bb[ni][0] = ldb(1, ni, 0); bb[ni][1] = ldb(1, ni, 1); }
    #pragma unroll
    for (int mi = 0; mi < 4; ++mi) { a03[mi][0] = lda(1, mi, 0); a03[mi][1] = lda(1, mi, 1); }
    if (!last) STG_A(0, 0, t + 2);
    asm volatile("s_waitcnt lgkmcnt(8)" ::: "memory");
    PH_SYNC(); MFMA_Q(0, a03, 0); PH_END();

    // ---- ph6: read bb23 (buf1, 4R); stage A(t+2)->buf0.h1
    #pragma unroll
    for (int ni = 2; ni < 4; ++ni) { bb[ni][0] = ldb(1, ni, 0); bb[ni][1] = ldb(1, ni, 1); }
    if (!last) STG_A(0, 1, t + 2);
    PH_SYNC(); MFMA_Q(0, a03, 2); PH_END();

    // ---- ph7: read a47 (buf1, 8R); stage B(t+3)->buf1.h0 (buf1.B reads retired ph6-END)
    #pragma unroll
    for (int mi = 0; mi < 4; ++mi) { a47[mi][0] = lda(1, 4 + mi, 0); a47[mi][1] = lda(1, 4 + mi, 1); }
    if (!last) STG_B(1, 0, t + 3);
    PH_SYNC(); MFMA_Q(4, a47, 0); PH_END();

    // ---- ph8: stage B(t+3)->buf1.h1; GATE tile t+2 (vmcnt(4): ph7/ph8's B(t+3) may fly)
    if (!last) STG_B(1, 1, t + 3);
    if (last) asm volatile("s_waitcnt vmcnt(0)" ::: "memory");
    else      asm volatile("s_waitcnt vmcnt(4)" ::: "memory");
    __builtin_amdgcn_s_barrier();
    asm volatile("s_waitcnt lgkmcnt(0)" ::: "memory");
    __builtin_amdgcn_s_setprio(1);
    MFMA_Q(4, a47, 2);
    __builtin_amdgcn_s_setprio(0);
    __builtin_amdgcn_s_barrier();
  }

  // ================= epilogue (byte-identical to verified round-2/round-4) =================
  // Step 1: ALL waves dump acc into full 256x256 bf16 X tile (exactly 128 KiB). acc dies here.
  int lq = l >> 4, lr = l & 15;
  int t0 = col0 >> 4;                      // first of this block's 16 targets

  float bias[4];
  #pragma unroll
  for (int ni = 0; ni < 4; ++ni) {
    int gcol = col0 + wc * 64 + ni * 16 + lr;
    bias[ni] = (gcol < O_REAL) ? b0[gcol] : 0.f;
  }

  #pragma unroll
  for (int mi = 0; mi < 8; ++mi) {
    #pragma unroll
    for (int ni = 0; ni < 4; ++ni) {
      #pragma unroll
      for (int r = 0; r < 4; ++r) {
        int rowL = wr * 128 + mi * 16 + lq * 4 + r;
        int colL = wc * 64 + ni * 16 + lr;
        int sw = ((rowL ^ (rowL >> 2)) & 7) << 4;
        float v = fmaxf(acc[mi][ni][r] + bias[ni], 0.f);
        *(unsigned short*)(smem + (size_t)rowL * 512 + ((colL * 2) ^ sw)) = f2bf(v);
      }
    }
  }
  __syncthreads();

  // Step 2: wave w owns targets 2w, 2w+1; lanes = rows. W via wave-uniform (scalar) loads.
  int uw = __builtin_amdgcn_readfirstlane(w);
  float oacc[2][4];
  #pragma unroll
  for (int g = 0; g < 2; ++g) {
    int tloc = uw * 2 + g;
    int tt = t0 + tloc;
    bool tvalid = (tt < NTGT);
    const float* w1t = W1g + (size_t)tt * 256;
    float b1v[16], w2v[16];
    float b2v = 0.f;
    if (tvalid) {
      #pragma unroll
      for (int e4 = 0; e4 < 4; ++e4) {
        float4 ba = *(const float4*)(b1g + (size_t)tt * 16 + e4 * 4);
        float4 wa = *(const float4*)(W2g + (size_t)tt * 16 + e4 * 4);
        b1v[e4 * 4 + 0] = ba.x; b1v[e4 * 4 + 1] = ba.y; b1v[e4 * 4 + 2] = ba.z; b1v[e4 * 4 + 3] = ba.w;
        w2v[e4 * 4 + 0] = wa.x; w2v[e4 * 4 + 1] = wa.y; w2v[e4 * 4 + 2] = wa.z; w2v[e4 * 4 + 3] = wa.w;
      }
      b2v = b2g[tt];
    }
    #pragma unroll
    for (int rg = 0; rg < 4; ++rg) {
      int rowL = rg * 64 + l;
      int sw = ((rowL ^ (rowL >> 2)) & 7) << 4;
      const char* bp = smem + (size_t)rowL * 512;
      uint4 va = *(const uint4*)(bp + ((tloc * 32) ^ sw));
      uint4 vb = *(const uint4*)(bp + ((tloc * 32 + 16) ^ sw));
      unsigned q0 = va.x, q1 = va.y, q2 = va.z, q3 = va.w;
      unsigned q4 = vb.x, q5 = vb.y, q6 = vb.z, q7 = vb.w;
      float x[16];
      x[0]  = __uint_as_float(q0 << 16); x[1]  = __uint_as_float(q0 & 0xffff0000u);
      x[2]  = __uint_as_float(q1 << 16); x[3]  = __uint_as_float(q1 & 0xffff0000u);
      x[4]  = __uint_as_float(q2 << 16); x[5]  = __uint_as_float(q2 & 0xffff0000u);
      x[6]  = __uint_as_float(q3 << 16); x[7]  = __uint_as_float(q3 & 0xffff0000u);
      x[8]  = __uint_as_float(q4 << 16); x[9]  = __uint_as_float(q4 & 0xffff0000u);
      x[10] = __uint_as_float(q5 << 16); x[11] = __uint_as_float(q5 & 0xffff0000u);
      x[12] = __uint_as_float(q6 << 16); x[13] = __uint_as_float(q6 & 0xffff0000u);
      x[14] = __uint_as_float(q7 << 16); x[15] = __uint_as_float(q7 & 0xffff0000u);
      float o = 0.f;
      if (tvalid) {
        #pragma unroll
        for (int e = 0; e < 16; ++e) {
          float4 wq0 = *(const float4*)(w1t + e * 16 + 0);
          float4 wq1 = *(const float4*)(w1t + e * 16 + 4);
          float4 wq2 = *(const float4*)(w1t + e * 16 + 8);
          float4 wq3 = *(const float4*)(w1t + e * 16 + 12);
          float s = b1v[e];
          s = fmaf(x[0],  wq0.x, s); s = fmaf(x[1],  wq0.y, s);
          s = fmaf(x[2],  wq0.z, s); s = fmaf(x[3],  wq0.w, s);
          s = fmaf(x[4],  wq1.x, s); s = fmaf(x[5],  wq1.y, s);
          s = fmaf(x[6],  wq1.z, s); s = fmaf(x[7],  wq1.w, s);
          s = fmaf(x[8],  wq2.x, s); s = fmaf(x[9],  wq2.y, s);
          s = fmaf(x[10], wq2.z, s); s = fmaf(x[11], wq2.w, s);
          s = fmaf(x[12], wq3.x, s); s = fmaf(x[13], wq3.y, s);
          s = fmaf(x[14], wq3.z, s); s = fmaf(x[15], wq3.w, s);
          s = fmaxf(s, 0.f);
          o = fmaf(s, w2v[e], o);
        }
        o += b2v;
      }
      oacc[g][rg] = o;
    }
  }
  __syncthreads();   // everyone done reading X

  // Step 3: transpose o through LDS ([256][17] f32 = 17.4 KB over dead X), coalesced out stores
  {
    float* sOut = (float*)smem;
    #pragma unroll
    for (int g = 0; g < 2; ++g) {
      int tloc = uw * 2 + g;
      #pragma unroll
      for (int rg = 0; rg < 4; ++rg)
        sOut[(rg * 64 + l) * 17 + tloc] = oacc[g][rg];
    }
    __syncthreads();
    int c = tid & 15, rr = tid >> 4;
    bool cv = (t0 + c < NTGT);
    #pragma unroll
    for (int j = 0; j < 8; ++j) {
      int row = rr + 32 * j;
      if (cv) out[(size_t)(row0 + row) * NTGT + (t0 + c)] = sOut[row * 17 + c];
    }
  }
#undef STG_A
#undef STG_B
#undef PH_SYNC
#undef PH_END
#undef MFMA_Q
}

extern "C" void kernel_launch(void* const* d_in, const int* in_sizes, int n_in,
                              void* d_out, int out_size, void* d_ws, size_t ws_size,
                              hipStream_t stream) {
  const float* AX = (const float*)d_in[0];
  const float* W0 = (const float*)d_in[1];
  const float* b0 = (const float*)d_in[2];
  const float* W1 = (const float*)d_in[3];
  const float* b1 = (const float*)d_in[4];
  const float* W2 = (const float*)d_in[5];
  const float* b2 = (const float*)d_in[6];
  float* out = (float*)d_out;

  char* ws = (char*)d_ws;
  const size_t szA = (size_t)NROW * KP * 2;     // 20.97 MB
  unsigned short* Ab = (unsigned short*)ws;
  unsigned short* Bb = (unsigned short*)(ws + szA);   // [8192][2560] bf16 = 41.9 MB

  hipFuncSetAttribute((const void*)gemm8, hipFuncAttributeMaxDynamicSharedMemorySize, 131072);

  convAll<<<NBLK_A + NBLK_B + NBLK_P, 256, 0, stream>>>(AX, W0, Ab, Bb);
  gemm8<<<(NROW / 256) * (NPAD / 256), 512, 131072, stream>>>(Ab, Bb, b0, W1, b1, W2, b2, out);
}

// Round 7
// 201.468 us; speedup vs baseline: 1.1108x; 1.0036x over previous
//
#include <hip/hip_runtime.h>
#include <hip/hip_bf16.h>
#include <stdint.h>

#define LAG 5
#define NROW 4096
#define NREG 500
#define NTGT 500
#define O_REAL 8000     /* HH*NTGT */
#define KP 2560         /* padded K = 40*64  (real K = 2500) */
#define NPAD 8192       /* GEMM N extent = 32*256 (cols >= 8000 masked) */
#define BK 64
#define NT 40           /* K-tiles */

#define NBLK_A 10240    /* NROW*(KP/4)/256 */
#define NBLK_B 15625    /* O_REAL*NREG/256 */
#define NBLK_P 949      /* ceil((O_REAL*15 + 192*(KP/4))/256) */

typedef __bf16 bf16x8 __attribute__((ext_vector_type(8)));
typedef float f32x4 __attribute__((ext_vector_type(4)));

__device__ __forceinline__ unsigned short f2bf(float f) {
  unsigned u = __float_as_uint(f);
  return (unsigned short)((u + 0x7fffu + ((u >> 16) & 1u)) >> 16);
}

__device__ __forceinline__ void async16(void* lds_base, const void* g) {
  __builtin_amdgcn_global_load_lds(
      (const __attribute__((address_space(1))) unsigned int*)g,
      (__attribute__((address_space(3))) unsigned int*)lds_base,
      16, 0, 0);
}

// ---- merged prep: convA [0,NBLK_A) | convB [NBLK_A,NBLK_A+NBLK_B) | padB [rest) ----------------
__global__ __launch_bounds__(256) void convAll(const float* __restrict__ AX,
                                               const float* __restrict__ W0,
                                               unsigned short* __restrict__ Ab,
                                               unsigned short* __restrict__ Bb) {
  int b = blockIdx.x;
  if (b < NBLK_A) {
    int idx = b * 256 + threadIdx.x;
    int n = idx / (KP / 4);
    int c4 = idx - n * (KP / 4);
    int k = c4 * 4;
    ushort4 o;
    if (k < LAG * NREG) {
      int l = k / NREG, r = k - l * NREG;
      float4 v = *(const float4*)(AX + ((size_t)l * NROW + n) * NREG + r);
      o.x = f2bf(v.x); o.y = f2bf(v.y); o.z = f2bf(v.z); o.w = f2bf(v.w);
    } else {
      o.x = 0; o.y = 0; o.z = 0; o.w = 0;
    }
    *(ushort4*)(Ab + (size_t)idx * 4) = o;
  } else if (b < NBLK_A + NBLK_B) {
    int idx = (b - NBLK_A) * 256 + threadIdx.x;
    int o = idx / NREG, r = idx - o * NREG;
    const float* s = W0 + (size_t)idx * LAG;
    #pragma unroll
    for (int j = 0; j < LAG; ++j)
      Bb[(size_t)o * KP + (size_t)(LAG - 1 - j) * NREG + r] = f2bf(s[j]);
  } else {
    int idx = (b - NBLK_A - NBLK_B) * 256 + threadIdx.x;    // ushort4 units
    const int A4 = O_REAL * 15;                             // 60 pad elems/row
    ushort4 z; z.x = 0; z.y = 0; z.z = 0; z.w = 0;
    if (idx < A4) {
      int row = idx / 15, c4 = idx - row * 15;
      *(ushort4*)(Bb + (size_t)row * KP + 2500 + c4 * 4) = z;
    } else {
      int j = idx - A4;
      if (j < 192 * (KP / 4))
        *(ushort4*)(Bb + (size_t)O_REAL * KP + (size_t)j * 4) = z;
    }
  }
}

// ---------------- 256x256 8-phase bf16 GEMM + fused MLP tail ------------------------------------
// K-loop v6: v4 skeleton with balanced reads 8/4/8/4 — bb01 reads moved from ph1/ph5 into the
// gate phases ph4/ph8, issued AFTER the vmcnt gate + barrier + lgkm0 and BEFORE the MFMA issue
// (target buffer guaranteed landed by the gate; return overlaps the gate phase's matrix drain).
// bb[] is loop-carried: written ph4/ph8/prologue, consumed ph1-ph3 / ph5-ph7.
// Hazard map unchanged: buf0.B reads retire ph2-END -> B(t+2) ph3/ph4; buf0.A retire ph3-END ->
// A(t+2) ph5/ph6; buf1.B retire ph6-END -> B(t+3) ph7/ph8; buf1.A retire ph7-END -> A(t+1) ph1/ph2.
__global__ __launch_bounds__(512, 2) void gemm8(const unsigned short* __restrict__ A,
                                                const unsigned short* __restrict__ B,
                                                const float* __restrict__ b0,
                                                const float* __restrict__ W1g,
                                                const float* __restrict__ b1g,
                                                const float* __restrict__ W2g,
                                                const float* __restrict__ b2g,
                                                float* __restrict__ out) {
  extern __shared__ char smem[];
  char* sAc = smem;            // [2][32768]
  char* sBc = smem + 65536;    // [2][32768]

  int bid = blockIdx.x;
  int swz = (bid & 7) * 64 + (bid >> 3);       // XCD-aware, bijective (512 % 8 == 0)
  int mt = swz & 15, ntile = swz >> 4;         // 16 M-tiles x 32 N-tiles
  int row0 = mt * 256, col0 = ntile * 256;

  int tid = threadIdx.x, l = tid & 63, w = tid >> 6;
  int wr = w >> 2, wc = w & 3;

  // staging source pointers (pre-swizzled global source, linear LDS dest)
  int sr = l >> 3;                 // row within 8-row chunk
  int ss = (l & 7) ^ sr;           // swizzled 16B slot
  const unsigned short* gApre0 = A + (size_t)(row0 + (w * 2 + 0) * 8 + sr) * KP + ss * 8;
  const unsigned short* gApre1 = A + (size_t)(row0 + (w * 2 + 1) * 8 + sr) * KP + ss * 8;
  const unsigned short* gBpre0 = B + (size_t)(col0 + (w * 2 + 0) * 8 + sr) * KP + ss * 8;
  const unsigned short* gBpre1 = B + (size_t)(col0 + (w * 2 + 1) * 8 + sr) * KP + ss * 8;

#define STG_A(buf, half, t) do { \
    async16(sAc + (buf) * 32768 + (half) * 16384 + (w * 2 + 0) * 1024, gApre0 + (size_t)(half) * 128 * KP + (size_t)(t) * BK); \
    async16(sAc + (buf) * 32768 + (half) * 16384 + (w * 2 + 1) * 1024, gApre1 + (size_t)(half) * 128 * KP + (size_t)(t) * BK); \
  } while (0)
#define STG_B(buf, half, t) do { \
    async16(sBc + (buf) * 32768 + (half) * 16384 + (w * 2 + 0) * 1024, gBpre0 + (size_t)(half) * 128 * KP + (size_t)(t) * BK); \
    async16(sBc + (buf) * 32768 + (half) * 16384 + (w * 2 + 1) * 1024, gBpre1 + (size_t)(half) * 128 * KP + (size_t)(t) * BK); \
  } while (0)

  // fragment read offsets (row&7 == l&7 for all fragment rows)
  int arowb = (wr * 128 + (l & 15)) * 128;     // byte offset of A row
  int browb = (wc * 64 + (l & 15)) * 128;      // byte offset of B row
  int c0 = (((l >> 4) << 4)) ^ ((l & 7) << 4); // kk=0 swizzled col byte; kk=1 -> ^64

  auto lda = [&](int buf, int mi, int kk) -> bf16x8 {
    return *(const bf16x8*)(sAc + buf * 32768 + arowb + mi * 2048 + (c0 ^ (kk * 64)));
  };
  auto ldb = [&](int buf, int ni, int kk) -> bf16x8 {
    return *(const bf16x8*)(sBc + buf * 32768 + browb + ni * 2048 + (c0 ^ (kk * 64)));
  };

  f32x4 acc[8][4];
  #pragma unroll
  for (int i = 0; i < 8; ++i)
    #pragma unroll
    for (int j = 0; j < 4; ++j) acc[i][j] = (f32x4){0.f, 0.f, 0.f, 0.f};

#define PH_SYNC() do { __builtin_amdgcn_s_barrier(); \
    asm volatile("s_waitcnt lgkmcnt(0)" ::: "memory"); \
    __builtin_amdgcn_s_setprio(1); } while (0)
#define PH_END() do { __builtin_amdgcn_s_setprio(0); __builtin_amdgcn_s_barrier(); } while (0)

#define MFMA_Q(MOFF, AF, NIOFF) do { \
    _Pragma("unroll") \
    for (int mi = 0; mi < 4; ++mi) { \
      _Pragma("unroll") \
      for (int ni = 0; ni < 2; ++ni) { \
        acc[(MOFF) + mi][(NIOFF) + ni] = __builtin_amdgcn_mfma_f32_16x16x32_bf16(AF[mi][0], bb[(NIOFF) + ni][0], acc[(MOFF) + mi][(NIOFF) + ni], 0, 0, 0); \
        acc[(MOFF) + mi][(NIOFF) + ni] = __builtin_amdgcn_mfma_f32_16x16x32_bf16(AF[mi][1], bb[(NIOFF) + ni][1], acc[(MOFF) + mi][(NIOFF) + ni], 0, 0, 0); \
      } \
    } \
  } while (0)

  // prologue: T0 full {B,A} + T1.B -> 12 loads/thread; gate T0 (T1.B's 4 in flight)
  STG_B(0, 0, 0); STG_B(0, 1, 0); STG_A(0, 0, 0); STG_A(0, 1, 0);
  STG_B(1, 0, 1); STG_B(1, 1, 1);
  asm volatile("s_waitcnt vmcnt(4)" ::: "memory");
  __builtin_amdgcn_s_barrier();

  bf16x8 bb[4][2];     // loop-carried: bb01 written in gate phases / prologue
  #pragma unroll
  for (int ni = 0; ni < 2; ++ni) { bb[ni][0] = ldb(0, ni, 0); bb[ni][1] = ldb(0, ni, 1); }

  for (int t = 0; t < NT; t += 2) {
    const bool last = (t == NT - 2);
    bf16x8 a03[4][2], a47[4][2];

    // ---- ph1: read a03 (buf0, 8R); stage A(t+1)->buf1.h0 (buf1.A reads retired prev ph7-END)
    #pragma unroll
    for (int mi = 0; mi < 4; ++mi) { a03[mi][0] = lda(0, mi, 0); a03[mi][1] = lda(0, mi, 1); }
    STG_A(1, 0, t + 1);
    PH_SYNC(); MFMA_Q(0, a03, 0); PH_END();

    // ---- ph2: read bb23 (4R); stage A(t+1)->buf1.h1
    #pragma unroll
    for (int ni = 2; ni < 4; ++ni) { bb[ni][0] = ldb(0, ni, 0); bb[ni][1] = ldb(0, ni, 1); }
    STG_A(1, 1, t + 1);
    PH_SYNC(); MFMA_Q(0, a03, 2); PH_END();

    // ---- ph3: read a47 (8R); stage B(t+2)->buf0.h0 (buf0.B reads retired ph2-END)
    #pragma unroll
    for (int mi = 0; mi < 4; ++mi) { a47[mi][0] = lda(0, 4 + mi, 0); a47[mi][1] = lda(0, 4 + mi, 1); }
    if (!last) STG_B(0, 0, t + 2);
    PH_SYNC(); MFMA_Q(4, a47, 0); PH_END();

    // ---- ph4: stage B(t+2)->buf0.h1; GATE tile t+1; post-gate read bb01(buf1) for ph5 (4R)
    if (!last) STG_B(0, 1, t + 2);
    if (last) asm volatile("s_waitcnt vmcnt(0)" ::: "memory");
    else      asm volatile("s_waitcnt vmcnt(4)" ::: "memory");
    __builtin_amdgcn_s_barrier();
    asm volatile("s_waitcnt lgkmcnt(0)" ::: "memory");
    #pragma unroll
    for (int ni = 0; ni < 2; ++ni) { bb[ni][0] = ldb(1, ni, 0); bb[ni][1] = ldb(1, ni, 1); }
    __builtin_amdgcn_s_setprio(1);
    MFMA_Q(4, a47, 2);
    PH_END();

    // ---- ph5: read a03 (buf1, 8R); stage A(t+2)->buf0.h0 (buf0.A reads retired ph3-END)
    #pragma unroll
    for (int mi = 0; mi < 4; ++mi) { a03[mi][0] = lda(1, mi, 0); a03[mi][1] = lda(1, mi, 1); }
    if (!last) STG_A(0, 0, t + 2);
    PH_SYNC(); MFMA_Q(0, a03, 0); PH_END();

    // ---- ph6: read bb23 (buf1, 4R); stage A(t+2)->buf0.h1
    #pragma unroll
    for (int ni = 2; ni < 4; ++ni) { bb[ni][0] = ldb(1, ni, 0); bb[ni][1] = ldb(1, ni, 1); }
    if (!last) STG_A(0, 1, t + 2);
    PH_SYNC(); MFMA_Q(0, a03, 2); PH_END();

    // ---- ph7: read a47 (buf1, 8R); stage B(t+3)->buf1.h0 (buf1.B reads retired ph6-END)
    #pragma unroll
    for (int mi = 0; mi < 4; ++mi) { a47[mi][0] = lda(1, 4 + mi, 0); a47[mi][1] = lda(1, 4 + mi, 1); }
    if (!last) STG_B(1, 0, t + 3);
    PH_SYNC(); MFMA_Q(4, a47, 0); PH_END();

    // ---- ph8: stage B(t+3)->buf1.h1; GATE tile t+2; post-gate read bb01(buf0 = T(t+2)) (4R)
    if (!last) STG_B(1, 1, t + 3);
    if (last) asm volatile("s_waitcnt vmcnt(0)" ::: "memory");
    else      asm volatile("s_waitcnt vmcnt(4)" ::: "memory");
    __builtin_amdgcn_s_barrier();
    asm volatile("s_waitcnt lgkmcnt(0)" ::: "memory");
    if (!last) {
      #pragma unroll
      for (int ni = 0; ni < 2; ++ni) { bb[ni][0] = ldb(0, ni, 0); bb[ni][1] = ldb(0, ni, 1); }
    }
    __builtin_amdgcn_s_setprio(1);
    MFMA_Q(4, a47, 2);
    __builtin_amdgcn_s_setprio(0);
    __builtin_amdgcn_s_barrier();
  }

  // ================= epilogue (byte-identical to verified round-2/round-4) =================
  // Step 1: ALL waves dump acc into full 256x256 bf16 X tile (exactly 128 KiB). acc dies here.
  int lq = l >> 4, lr = l & 15;
  int t0 = col0 >> 4;                      // first of this block's 16 targets

  float bias[4];
  #pragma unroll
  for (int ni = 0; ni < 4; ++ni) {
    int gcol = col0 + wc * 64 + ni * 16 + lr;
    bias[ni] = (gcol < O_REAL) ? b0[gcol] : 0.f;
  }

  #pragma unroll
  for (int mi = 0; mi < 8; ++mi) {
    #pragma unroll
    for (int ni = 0; ni < 4; ++ni) {
      #pragma unroll
      for (int r = 0; r < 4; ++r) {
        int rowL = wr * 128 + mi * 16 + lq * 4 + r;
        int colL = wc * 64 + ni * 16 + lr;
        int sw = ((rowL ^ (rowL >> 2)) & 7) << 4;
        float v = fmaxf(acc[mi][ni][r] + bias[ni], 0.f);
        *(unsigned short*)(smem + (size_t)rowL * 512 + ((colL * 2) ^ sw)) = f2bf(v);
      }
    }
  }
  __syncthreads();

  // Step 2: wave w owns targets 2w, 2w+1; lanes = rows. W via wave-uniform (scalar) loads.
  int uw = __builtin_amdgcn_readfirstlane(w);
  float oacc[2][4];
  #pragma unroll
  for (int g = 0; g < 2; ++g) {
    int tloc = uw * 2 + g;
    int tt = t0 + tloc;
    bool tvalid = (tt < NTGT);
    const float* w1t = W1g + (size_t)tt * 256;
    float b1v[16], w2v[16];
    float b2v = 0.f;
    if (tvalid) {
      #pragma unroll
      for (int e4 = 0; e4 < 4; ++e4) {
        float4 ba = *(const float4*)(b1g + (size_t)tt * 16 + e4 * 4);
        float4 wa = *(const float4*)(W2g + (size_t)tt * 16 + e4 * 4);
        b1v[e4 * 4 + 0] = ba.x; b1v[e4 * 4 + 1] = ba.y; b1v[e4 * 4 + 2] = ba.z; b1v[e4 * 4 + 3] = ba.w;
        w2v[e4 * 4 + 0] = wa.x; w2v[e4 * 4 + 1] = wa.y; w2v[e4 * 4 + 2] = wa.z; w2v[e4 * 4 + 3] = wa.w;
      }
      b2v = b2g[tt];
    }
    #pragma unroll
    for (int rg = 0; rg < 4; ++rg) {
      int rowL = rg * 64 + l;
      int sw = ((rowL ^ (rowL >> 2)) & 7) << 4;
      const char* bp = smem + (size_t)rowL * 512;
      uint4 va = *(const uint4*)(bp + ((tloc * 32) ^ sw));
      uint4 vb = *(const uint4*)(bp + ((tloc * 32 + 16) ^ sw));
      unsigned q0 = va.x, q1 = va.y, q2 = va.z, q3 = va.w;
      unsigned q4 = vb.x, q5 = vb.y, q6 = vb.z, q7 = vb.w;
      float x[16];
      x[0]  = __uint_as_float(q0 << 16); x[1]  = __uint_as_float(q0 & 0xffff0000u);
      x[2]  = __uint_as_float(q1 << 16); x[3]  = __uint_as_float(q1 & 0xffff0000u);
      x[4]  = __uint_as_float(q2 << 16); x[5]  = __uint_as_float(q2 & 0xffff0000u);
      x[6]  = __uint_as_float(q3 << 16); x[7]  = __uint_as_float(q3 & 0xffff0000u);
      x[8]  = __uint_as_float(q4 << 16); x[9]  = __uint_as_float(q4 & 0xffff0000u);
      x[10] = __uint_as_float(q5 << 16); x[11] = __uint_as_float(q5 & 0xffff0000u);
      x[12] = __uint_as_float(q6 << 16); x[13] = __uint_as_float(q6 & 0xffff0000u);
      x[14] = __uint_as_float(q7 << 16); x[15] = __uint_as_float(q7 & 0xffff0000u);
      float o = 0.f;
      if (tvalid) {
        #pragma unroll
        for (int e = 0; e < 16; ++e) {
          float4 wq0 = *(const float4*)(w1t + e * 16 + 0);
          float4 wq1 = *(const float4*)(w1t + e * 16 + 4);
          float4 wq2 = *(const float4*)(w1t + e * 16 + 8);
          float4 wq3 = *(const float4*)(w1t + e * 16 + 12);
          float s = b1v[e];
          s = fmaf(x[0],  wq0.x, s); s = fmaf(x[1],  wq0.y, s);
          s = fmaf(x[2],  wq0.z, s); s = fmaf(x[3],  wq0.w, s);
          s = fmaf(x[4],  wq1.x, s); s = fmaf(x[5],  wq1.y, s);
          s = fmaf(x[6],  wq1.z, s); s = fmaf(x[7],  wq1.w, s);
          s = fmaf(x[8],  wq2.x, s); s = fmaf(x[9],  wq2.y, s);
          s = fmaf(x[10], wq2.z, s); s = fmaf(x[11], wq2.w, s);
          s = fmaf(x[12], wq3.x, s); s = fmaf(x[13], wq3.y, s);
          s = fmaf(x[14], wq3.z, s); s = fmaf(x[15], wq3.w, s);
          s = fmaxf(s, 0.f);
          o = fmaf(s, w2v[e], o);
        }
        o += b2v;
      }
      oacc[g][rg] = o;
    }
  }
  __syncthreads();   // everyone done reading X

  // Step 3: transpose o through LDS ([256][17] f32 = 17.4 KB over dead X), coalesced out stores
  {
    float* sOut = (float*)smem;
    #pragma unroll
    for (int g = 0; g < 2; ++g) {
      int tloc = uw * 2 + g;
      #pragma unroll
      for (int rg = 0; rg < 4; ++rg)
        sOut[(rg * 64 + l) * 17 + tloc] = oacc[g][rg];
    }
    __syncthreads();
    int c = tid & 15, rr = tid >> 4;
    bool cv = (t0 + c < NTGT);
    #pragma unroll
    for (int j = 0; j < 8; ++j) {
      int row = rr + 32 * j;
      if (cv) out[(size_t)(row0 + row) * NTGT + (t0 + c)] = sOut[row * 17 + c];
    }
  }
#undef STG_A
#undef STG_B
#undef PH_SYNC
#undef PH_END
#undef MFMA_Q
}

extern "C" void kernel_launch(void* const* d_in, const int* in_sizes, int n_in,
                              void* d_out, int out_size, void* d_ws, size_t ws_size,
                              hipStream_t stream) {
  const float* AX = (const float*)d_in[0];
  const float* W0 = (const float*)d_in[1];
  const float* b0 = (const float*)d_in[2];
  const float* W1 = (const float*)d_in[3];
  const float* b1 = (const float*)d_in[4];
  const float* W2 = (const float*)d_in[5];
  const float* b2 = (const float*)d_in[6];
  float* out = (float*)d_out;

  char* ws = (char*)d_ws;
  const size_t szA = (size_t)NROW * KP * 2;     // 20.97 MB
  unsigned short* Ab = (unsigned short*)ws;
  unsigned short* Bb = (unsigned short*)(ws + szA);   // [8192][2560] bf16 = 41.9 MB

  hipFuncSetAttribute((const void*)gemm8, hipFuncAttributeMaxDynamicSharedMemorySize, 131072);

  convAll<<<NBLK_A + NBLK_B + NBLK_P, 256, 0, stream>>>(AX, W0, Ab, Bb);
  gemm8<<<(NROW / 256) * (NPAD / 256), 512, 131072, stream>>>(Ab, Bb, b0, W1, b1, W2, b2, out);
}